// Round 1
// baseline (1956.294 us; speedup 1.0000x reference)
//
#include <hip/hip_runtime.h>
#include <math.h>

#define NEG_SLOPE 0.2f

// ---------- helpers ----------
__device__ __forceinline__ unsigned enc_f(float f){
  unsigned u = __float_as_uint(f);
  return (u & 0x80000000u) ? ~u : (u | 0x80000000u);
}
__device__ __forceinline__ float dec_f(unsigned u){
  return __uint_as_float((u & 0x80000000u) ? (u ^ 0x80000000u) : ~u);
}
#define ENC_NEG_INF 0x007FFFFFu   // enc(-inf)

__global__ void fill_u32_k(unsigned* __restrict__ p, unsigned v, int n){
  int i = blockIdx.x * blockDim.x + threadIdx.x;
  if (i < n) p[i] = v;
}

// ---------- dense transform: h = X*W, alpha_s/d per head ----------
// X: [N,FIN], W: [FIN,128] row-major, a_s/a_d: [128] (= [4,32] flat)
// launch: blockDim=128, dyn smem = FIN*128*4
template<int FIN>
__global__ void transform_k(const float* __restrict__ X, const float* __restrict__ W,
                            const float* __restrict__ a_s, const float* __restrict__ a_d,
                            float* __restrict__ h, float* __restrict__ as_, float* __restrict__ ad_,
                            int N){
  extern __shared__ float sW[];
  for (int i = threadIdx.x; i < FIN*128; i += blockDim.x) sW[i] = W[i];
  __syncthreads();
  const int t = threadIdx.x;               // t = head*32 + c
  const float ras = a_s[t], rad = a_d[t];
  for (int n = blockIdx.x; n < N; n += gridDim.x){
    float acc = 0.f;
    #pragma unroll 8
    for (int k = 0; k < FIN; ++k) acc += X[(size_t)n*FIN + k] * sW[k*128 + t];
    h[(size_t)n*128 + t] = acc;
    float vs = acc * ras, vd = acc * rad;
    #pragma unroll
    for (int off = 16; off > 0; off >>= 1){
      vs += __shfl_down(vs, off, 32);
      vd += __shfl_down(vd, off, 32);
    }
    if ((t & 31) == 0){ as_[n*4 + (t>>5)] = vs; ad_[n*4 + (t>>5)] = vd; }
  }
}

// ---------- edge pass A: e = leaky(as[src]+ad[dst]); m[dst] = max ----------
__global__ void edge_e_max(const int* __restrict__ esrc, const int* __restrict__ edst,
                           const float4* __restrict__ as_, const float4* __restrict__ ad_,
                           float4* __restrict__ p, unsigned* __restrict__ m,
                           int Eg, int Etot){
  int e = blockIdx.x * blockDim.x + threadIdx.x;
  if (e >= Etot) return;
  int s, d;
  if (e < Eg){ s = esrc[e]; d = edst[e]; } else { s = d = e - Eg; }
  float4 a = as_[s], b = ad_[d];
  float4 ev;
  ev.x = a.x + b.x; ev.x = ev.x > 0.f ? ev.x : NEG_SLOPE * ev.x;
  ev.y = a.y + b.y; ev.y = ev.y > 0.f ? ev.y : NEG_SLOPE * ev.y;
  ev.z = a.z + b.z; ev.z = ev.z > 0.f ? ev.z : NEG_SLOPE * ev.z;
  ev.w = a.w + b.w; ev.w = ev.w > 0.f ? ev.w : NEG_SLOPE * ev.w;
  p[e] = ev;
  atomicMax(&m[d*4 + 0], enc_f(ev.x));
  atomicMax(&m[d*4 + 1], enc_f(ev.y));
  atomicMax(&m[d*4 + 2], enc_f(ev.z));
  atomicMax(&m[d*4 + 3], enc_f(ev.w));
}

// ---------- edge pass B: p = exp(e - m[dst]); s[dst] += p ----------
__global__ void edge_exp_sum(const int* __restrict__ edst,
                             float4* __restrict__ p, const unsigned* __restrict__ m,
                             float* __restrict__ s, int Eg, int Etot){
  int e = blockIdx.x * blockDim.x + threadIdx.x;
  if (e >= Etot) return;
  int d = (e < Eg) ? edst[e] : (e - Eg);
  float4 ev = p[e];
  float4 pv;
  pv.x = __expf(0.f); // placeholder avoided below; use expf for accuracy
  pv.x = expf(ev.x - dec_f(m[d*4 + 0]));
  pv.y = expf(ev.y - dec_f(m[d*4 + 1]));
  pv.z = expf(ev.z - dec_f(m[d*4 + 2]));
  pv.w = expf(ev.w - dec_f(m[d*4 + 3]));
  p[e] = pv;
  unsafeAtomicAdd(&s[d*4 + 0], pv.x);
  unsafeAtomicAdd(&s[d*4 + 1], pv.y);
  unsafeAtomicAdd(&s[d*4 + 2], pv.z);
  unsafeAtomicAdd(&s[d*4 + 3], pv.w);
}

// ---------- edge pass C: out[dst, :] += h[src, :] * (p/s[dst]) ----------
// blockDim=256 -> 2 edges per block, 128 threads (channels) per edge
__global__ void edge_aggr(const int* __restrict__ esrc, const int* __restrict__ edst,
                          const float* __restrict__ p, const float* __restrict__ s,
                          const float* __restrict__ h, float* __restrict__ out,
                          int Eg, int Etot){
  int e = blockIdx.x * 2 + (threadIdx.x >> 7);
  if (e >= Etot) return;
  int t = threadIdx.x & 127;
  int hd = t >> 5;
  int sn, d;
  if (e < Eg){ sn = esrc[e]; d = edst[e]; } else { sn = d = e - Eg; }
  float alpha = p[e*4 + hd] / s[d*4 + hd];
  unsafeAtomicAdd(&out[(size_t)d*128 + t], h[(size_t)sn*128 + t] * alpha);
}

// ---------- bias + elu (in place) ----------
__global__ void bias_elu_k(float* __restrict__ x, const float* __restrict__ b, int total){
  int i = blockIdx.x * blockDim.x + threadIdx.x;
  if (i < total){
    float v = x[i] + b[i & 127];
    x[i] = v > 0.f ? v : expm1f(v);
  }
}

// ---------- layer 3 (H=1, C=1) ----------
__global__ void transform3_k(const float* __restrict__ X, const float* __restrict__ W3,
                             const float* __restrict__ a_s3, const float* __restrict__ a_d3,
                             float* __restrict__ h3, float* __restrict__ as_, float* __restrict__ ad_,
                             int N){
  __shared__ float sW[128];
  if (threadIdx.x < 128) sW[threadIdx.x] = W3[threadIdx.x];
  __syncthreads();
  int n = blockIdx.x * blockDim.x + threadIdx.x;
  if (n >= N) return;
  float acc = 0.f;
  #pragma unroll 8
  for (int k = 0; k < 128; ++k) acc += X[(size_t)n*128 + k] * sW[k];
  h3[n] = acc;
  as_[n] = acc * a_s3[0];
  ad_[n] = acc * a_d3[0];
}

__global__ void edge_e_max1(const int* __restrict__ esrc, const int* __restrict__ edst,
                            const float* __restrict__ as_, const float* __restrict__ ad_,
                            float* __restrict__ p, unsigned* __restrict__ m,
                            int Eg, int Etot){
  int e = blockIdx.x * blockDim.x + threadIdx.x;
  if (e >= Etot) return;
  int s, d;
  if (e < Eg){ s = esrc[e]; d = edst[e]; } else { s = d = e - Eg; }
  float v = as_[s] + ad_[d];
  v = v > 0.f ? v : NEG_SLOPE * v;
  p[e] = v;
  atomicMax(&m[d], enc_f(v));
}

__global__ void edge_exp_sum1(const int* __restrict__ edst,
                              float* __restrict__ p, const unsigned* __restrict__ m,
                              float* __restrict__ s, int Eg, int Etot){
  int e = blockIdx.x * blockDim.x + threadIdx.x;
  if (e >= Etot) return;
  int d = (e < Eg) ? edst[e] : (e - Eg);
  float pv = expf(p[e] - dec_f(m[d]));
  p[e] = pv;
  unsafeAtomicAdd(&s[d], pv);
}

__global__ void edge_aggr1(const int* __restrict__ esrc, const int* __restrict__ edst,
                           const float* __restrict__ p, const float* __restrict__ s,
                           const float* __restrict__ h3, float* __restrict__ out,
                           int Eg, int Etot){
  int e = blockIdx.x * blockDim.x + threadIdx.x;
  if (e >= Etot) return;
  int sn, d;
  if (e < Eg){ sn = esrc[e]; d = edst[e]; } else { sn = d = e - Eg; }
  float alpha = p[e] / s[d];
  unsafeAtomicAdd(&out[d], h3[sn] * alpha);
}

__global__ void final_bias_k(const float* __restrict__ o, const float* __restrict__ b3,
                             float* __restrict__ y, int N){
  int i = blockIdx.x * blockDim.x + threadIdx.x;
  if (i < N) y[i] = o[i] + b3[0];
}

// ---------- launch ----------
extern "C" void kernel_launch(void* const* d_in, const int* in_sizes, int n_in,
                              void* d_out, int out_size, void* d_ws, size_t ws_size,
                              hipStream_t stream){
  const float* x   = (const float*)d_in[0];
  const int*   ei  = (const int*)  d_in[1];
  const float* W1  = (const float*)d_in[2];
  const float* as1 = (const float*)d_in[3];
  const float* ad1 = (const float*)d_in[4];
  const float* b1  = (const float*)d_in[5];
  const float* W2  = (const float*)d_in[6];
  const float* as2 = (const float*)d_in[7];
  const float* ad2 = (const float*)d_in[8];
  const float* b2  = (const float*)d_in[9];
  const float* W3  = (const float*)d_in[10];
  const float* as3 = (const float*)d_in[11];
  const float* ad3 = (const float*)d_in[12];
  const float* b3  = (const float*)d_in[13];

  const int N    = in_sizes[0];       // IN_C = 1
  const int Eg   = in_sizes[1] / 2;
  const int Etot = Eg + N;
  const int* esrc = ei;
  const int* edst = ei + Eg;

  // workspace carve (all offsets multiples of 16B)
  char* w = (char*)d_ws;
  float* hbuf = (float*)w;  w += (size_t)N * 128 * 4;
  float* bufA = (float*)w;  w += (size_t)N * 128 * 4;
  float* bufB = (float*)w;  w += (size_t)N * 128 * 4;
  float* pbuf = (float*)w;  w += (size_t)Etot * 4 * 4;
  float* asb  = (float*)w;  w += (size_t)N * 4 * 4;
  float* adb  = (float*)w;  w += (size_t)N * 4 * 4;
  unsigned* mbuf = (unsigned*)w; w += (size_t)N * 4 * 4;
  float* sbuf = (float*)w;  w += (size_t)N * 4 * 4;

  const int B = 256;
  auto cdiv = [](int a, int b){ return (a + b - 1) / b; };

  // ---------------- layer 1 ----------------
  transform_k<1><<<2048, 128, 1*128*4, stream>>>(x, W1, as1, ad1, hbuf, asb, adb, N);
  fill_u32_k<<<cdiv(N*4, B), B, 0, stream>>>(mbuf, ENC_NEG_INF, N*4);
  fill_u32_k<<<cdiv(N*4, B), B, 0, stream>>>((unsigned*)sbuf, 0u, N*4);
  fill_u32_k<<<cdiv(N*128, B), B, 0, stream>>>((unsigned*)bufA, 0u, N*128);
  edge_e_max<<<cdiv(Etot, B), B, 0, stream>>>(esrc, edst, (const float4*)asb, (const float4*)adb,
                                              (float4*)pbuf, mbuf, Eg, Etot);
  edge_exp_sum<<<cdiv(Etot, B), B, 0, stream>>>(edst, (float4*)pbuf, mbuf, sbuf, Eg, Etot);
  edge_aggr<<<cdiv(Etot, 2), B, 0, stream>>>(esrc, edst, pbuf, sbuf, hbuf, bufA, Eg, Etot);
  bias_elu_k<<<cdiv(N*128, B), B, 0, stream>>>(bufA, b1, N*128);

  // ---------------- layer 2 ----------------
  transform_k<128><<<2048, 128, 128*128*4, stream>>>(bufA, W2, as2, ad2, hbuf, asb, adb, N);
  fill_u32_k<<<cdiv(N*4, B), B, 0, stream>>>(mbuf, ENC_NEG_INF, N*4);
  fill_u32_k<<<cdiv(N*4, B), B, 0, stream>>>((unsigned*)sbuf, 0u, N*4);
  fill_u32_k<<<cdiv(N*128, B), B, 0, stream>>>((unsigned*)bufB, 0u, N*128);
  edge_e_max<<<cdiv(Etot, B), B, 0, stream>>>(esrc, edst, (const float4*)asb, (const float4*)adb,
                                              (float4*)pbuf, mbuf, Eg, Etot);
  edge_exp_sum<<<cdiv(Etot, B), B, 0, stream>>>(edst, (float4*)pbuf, mbuf, sbuf, Eg, Etot);
  edge_aggr<<<cdiv(Etot, 2), B, 0, stream>>>(esrc, edst, pbuf, sbuf, hbuf, bufB, Eg, Etot);
  bias_elu_k<<<cdiv(N*128, B), B, 0, stream>>>(bufB, b2, N*128);

  // ---------------- layer 3 (H=1,C=1) ----------------
  transform3_k<<<cdiv(N, B), B, 0, stream>>>(bufB, W3, as3, ad3, hbuf, asb, adb, N);
  fill_u32_k<<<cdiv(N, B), B, 0, stream>>>(mbuf, ENC_NEG_INF, N);
  fill_u32_k<<<cdiv(N, B), B, 0, stream>>>((unsigned*)sbuf, 0u, N);
  fill_u32_k<<<cdiv(N, B), B, 0, stream>>>((unsigned*)bufA, 0u, N);
  edge_e_max1<<<cdiv(Etot, B), B, 0, stream>>>(esrc, edst, asb, adb, pbuf, mbuf, Eg, Etot);
  edge_exp_sum1<<<cdiv(Etot, B), B, 0, stream>>>(edst, pbuf, mbuf, sbuf, Eg, Etot);
  edge_aggr1<<<cdiv(Etot, B), B, 0, stream>>>(esrc, edst, pbuf, sbuf, hbuf, bufA, Eg, Etot);
  final_bias_k<<<cdiv(N, B), B, 0, stream>>>(bufA, b3, (float*)d_out, N);
}

// Round 2
// 765.488 us; speedup vs baseline: 2.5556x; 2.5556x over previous
//
#include <hip/hip_runtime.h>
#include <math.h>

#define NEG_SLOPE 0.2f

static __device__ __forceinline__ float leaky(float v){ return v > 0.f ? v : NEG_SLOPE * v; }

// ---------------- CSR build ----------------
__global__ void fill_i32_k(int* __restrict__ p, int v, int n){
  int i = blockIdx.x * blockDim.x + threadIdx.x;
  if (i < n) p[i] = v;
}

__global__ void hist_k(const int* __restrict__ edst, int* __restrict__ deg, int Eg, int Etot){
  int e = blockIdx.x * blockDim.x + threadIdx.x;
  if (e >= Etot) return;
  int d = (e < Eg) ? edst[e] : (e - Eg);
  atomicAdd(&deg[d], 1);
}

// single block, 1024 threads: exclusive scan of deg[N] -> row[N+1], copy to cursor
__global__ void __launch_bounds__(1024) scan_k(const int* __restrict__ deg,
                                               int* __restrict__ row, int* __restrict__ cursor, int N){
  __shared__ int part[1024];
  const int t = threadIdx.x;
  const int per = (N + 1023) / 1024;
  const int base = t * per;
  int sum = 0;
  for (int i = 0; i < per; ++i){ int idx = base + i; if (idx < N) sum += deg[idx]; }
  part[t] = sum; __syncthreads();
  for (int off = 1; off < 1024; off <<= 1){
    int v = (t >= off) ? part[t - off] : 0;
    __syncthreads();
    part[t] += v;
    __syncthreads();
  }
  int run = (t == 0) ? 0 : part[t - 1];
  for (int i = 0; i < per; ++i){
    int idx = base + i;
    if (idx < N){ row[idx] = run; cursor[idx] = run; run += deg[idx]; }
  }
  if (t == 1023) row[N] = part[1023];
}

__global__ void scatter_k(const int* __restrict__ esrc, const int* __restrict__ edst,
                          int* __restrict__ cursor, int* __restrict__ csr_src, int Eg, int Etot){
  int e = blockIdx.x * blockDim.x + threadIdx.x;
  if (e >= Etot) return;
  int s, d;
  if (e < Eg){ s = esrc[e]; d = edst[e]; } else { s = d = e - Eg; }
  int pos = atomicAdd(&cursor[d], 1);
  csr_src[pos] = s;
}

// ---------------- layer 1 (Fin = 1) ----------------
// dA[h] = sum_c W1[h*32+c]*a_s1[h*32+c]; dD likewise.  one block of 128 threads.
__global__ void dots1_k(const float* __restrict__ W1, const float* __restrict__ a_s,
                        const float* __restrict__ a_d, float* __restrict__ dAdD){
  int t = threadIdx.x;
  float ps = W1[t] * a_s[t];
  float pd = W1[t] * a_d[t];
  #pragma unroll
  for (int off = 16; off; off >>= 1){
    ps += __shfl_xor(ps, off, 32);
    pd += __shfl_xor(pd, off, 32);
  }
  if ((t & 31) == 0){ dAdD[t >> 5] = ps; dAdD[4 + (t >> 5)] = pd; }
}

// h[n][c] = x[n]*W1[c] (float4 over c); and as_[n][h] = x[n]*dA[h]
__global__ void transform1_k(const float* __restrict__ x, const float* __restrict__ W1,
                             const float* __restrict__ dAdD,
                             float4* __restrict__ h4, float* __restrict__ as_, float* __restrict__ ad_,
                             int N){
  int idx = blockIdx.x * blockDim.x + threadIdx.x;   // over N*32
  if (idx >= N * 32) return;
  int n = idx >> 5, c4 = idx & 31;
  float xv = x[n];
  float4 w = ((const float4*)W1)[c4];
  float4 o; o.x = xv * w.x; o.y = xv * w.y; o.z = xv * w.z; o.w = xv * w.w;
  h4[idx] = o;
  if (c4 < 4){
    as_[n * 4 + c4] = xv * dAdD[c4];
    ad_[n * 4 + c4] = xv * dAdD[4 + c4];
  }
}

// ---------------- per-node softmax + aggregate (layers 1,2) ----------------
// 128 threads per node (2 nodes / 256-block). thread c: head = c>>5, lane j = c&31.
template<bool DO_ELU>
__global__ void __launch_bounds__(256) node_aggr_k(const int* __restrict__ row, const int* __restrict__ csr_src,
                                                   const float* __restrict__ as_, const float* __restrict__ ad_,
                                                   const float* __restrict__ h, const float* __restrict__ bias,
                                                   float* __restrict__ out, int N){
  int node = blockIdx.x * 2 + (threadIdx.x >> 7);
  if (node >= N) return;
  const int c  = threadIdx.x & 127;
  const int hd = c >> 5;
  const int j  = c & 31;
  const int start = row[node], end = row[node + 1];
  const float adv = ad_[node * 4 + hd];

  // per-head max over incoming edges (32 lanes stride the edge list)
  float m = -INFINITY;
  for (int i = start + j; i < end; i += 32){
    int src = csr_src[i];
    m = fmaxf(m, leaky(as_[src * 4 + hd] + adv));
  }
  #pragma unroll
  for (int off = 16; off; off >>= 1) m = fmaxf(m, __shfl_xor(m, off, 32));

  // single serial pass: every thread accumulates s (redundant per lane) and its channel
  float s = 0.f, acc = 0.f;
  for (int i = start; i < end; ++i){
    int src = csr_src[i];
    float p = expf(leaky(as_[src * 4 + hd] + adv) - m);
    s   += p;
    acc += h[(size_t)src * 128 + c] * p;
  }
  float v = acc / s + bias[c];
  if (DO_ELU) v = v > 0.f ? v : expm1f(v);
  out[(size_t)node * 128 + c] = v;
}

// ---------------- layer 2 dense: h = A(Nx128) * W(128x128), alphas fused ----------------
// block 256: 64 nodes x 128 cols; thread tile 4 nodes x 8 cols.
__global__ void __launch_bounds__(256) gemm2_k(const float* __restrict__ A, const float* __restrict__ W,
                                               const float* __restrict__ a_s, const float* __restrict__ a_d,
                                               float* __restrict__ h, float* __restrict__ as_, float* __restrict__ ad_,
                                               int N){
  __shared__ float sW[128 * 128];     // 64 KB
  __shared__ float sA[64 * 129];      // 33 KB (padded, +1 breaks bank aliasing)
  const int t = threadIdx.x;
  const int n0 = blockIdx.x * 64;

  // stage W (coalesced float4)
  {
    const float4* W4 = (const float4*)W;
    float4* sW4 = (float4*)sW;
    #pragma unroll
    for (int i = 0; i < 16; ++i) sW4[t + 256 * i] = W4[t + 256 * i];
  }
  // stage A tile (64 rows x 128)
  for (int idx = t; idx < 64 * 128; idx += 256){
    int r = idx >> 7, k = idx & 127;
    int gr = n0 + r;
    sA[r * 129 + k] = (gr < N) ? A[(size_t)gr * 128 + k] : 0.f;
  }
  __syncthreads();

  const int tc = t & 15;        // col group: cols [tc*8, tc*8+8), head = tc>>2
  const int tn = t >> 4;        // node group: rows [tn*4, tn*4+4)
  const int c0 = tc * 8;
  const int r0 = tn * 4;

  float acc[4][8];
  #pragma unroll
  for (int r = 0; r < 4; ++r)
    #pragma unroll
    for (int cc = 0; cc < 8; ++cc) acc[r][cc] = 0.f;

  const float4* sW4 = (const float4*)sW;
  #pragma unroll 4
  for (int k = 0; k < 128; ++k){
    float a0 = sA[(r0 + 0) * 129 + k];
    float a1 = sA[(r0 + 1) * 129 + k];
    float a2 = sA[(r0 + 2) * 129 + k];
    float a3 = sA[(r0 + 3) * 129 + k];
    float4 wa = sW4[k * 32 + tc * 2];
    float4 wb = sW4[k * 32 + tc * 2 + 1];
    float w[8] = {wa.x, wa.y, wa.z, wa.w, wb.x, wb.y, wb.z, wb.w};
    #pragma unroll
    for (int cc = 0; cc < 8; ++cc){
      acc[0][cc] += a0 * w[cc];
      acc[1][cc] += a1 * w[cc];
      acc[2][cc] += a2 * w[cc];
      acc[3][cc] += a3 * w[cc];
    }
  }

  // epilogue: write h (float4 x2 per row) + fused alpha partial reduction
  float asv[8], adv[8];
  #pragma unroll
  for (int cc = 0; cc < 8; ++cc){ asv[cc] = a_s[c0 + cc]; adv[cc] = a_d[c0 + cc]; }

  #pragma unroll
  for (int r = 0; r < 4; ++r){
    int n = n0 + r0 + r;
    if (n >= N) continue;
    float4 o0 = make_float4(acc[r][0], acc[r][1], acc[r][2], acc[r][3]);
    float4 o1 = make_float4(acc[r][4], acc[r][5], acc[r][6], acc[r][7]);
    float4* hp = (float4*)&h[(size_t)n * 128 + c0];
    hp[0] = o0; hp[1] = o1;
    float ps = 0.f, pd = 0.f;
    #pragma unroll
    for (int cc = 0; cc < 8; ++cc){ ps += acc[r][cc] * asv[cc]; pd += acc[r][cc] * adv[cc]; }
    ps += __shfl_xor(ps, 1); ps += __shfl_xor(ps, 2);
    pd += __shfl_xor(pd, 1); pd += __shfl_xor(pd, 2);
    if ((t & 3) == 0){
      as_[n * 4 + (tc >> 2)] = ps;
      ad_[n * 4 + (tc >> 2)] = pd;
    }
  }
}

// ---------------- layer 3 ----------------
// h3[n] = dot(act2[n,:], W3); 32 lanes per node, float4 loads.
__global__ void __launch_bounds__(256) transform3_k(const float* __restrict__ A, const float* __restrict__ W3,
                                                    const float* __restrict__ a_s3, const float* __restrict__ a_d3,
                                                    float* __restrict__ h3, float* __restrict__ as_, float* __restrict__ ad_,
                                                    int N){
  int node = blockIdx.x * 8 + (threadIdx.x >> 5);
  if (node >= N) return;
  int j = threadIdx.x & 31;
  float4 a = ((const float4*)A)[(size_t)node * 32 + j];
  float4 w = ((const float4*)W3)[j];
  float acc = a.x * w.x + a.y * w.y + a.z * w.z + a.w * w.w;
  #pragma unroll
  for (int off = 16; off; off >>= 1) acc += __shfl_xor(acc, off, 32);
  if (j == 0){
    h3[node]  = acc;
    as_[node] = acc * a_s3[0];
    ad_[node] = acc * a_d3[0];
  }
}

// one 64-lane wave per node
__global__ void __launch_bounds__(256) node_aggr3_k(const int* __restrict__ row, const int* __restrict__ csr_src,
                                                    const float* __restrict__ as_, const float* __restrict__ ad_,
                                                    const float* __restrict__ h3, const float* __restrict__ b3,
                                                    float* __restrict__ out, int N){
  int node = blockIdx.x * 4 + (threadIdx.x >> 6);
  if (node >= N) return;
  int j = threadIdx.x & 63;
  int start = row[node], end = row[node + 1];
  float adv = ad_[node];
  float m = -INFINITY;
  for (int i = start + j; i < end; i += 64)
    m = fmaxf(m, leaky(as_[csr_src[i]] + adv));
  #pragma unroll
  for (int off = 32; off; off >>= 1) m = fmaxf(m, __shfl_xor(m, off));
  float s = 0.f, acc = 0.f;
  for (int i = start + j; i < end; i += 64){
    int src = csr_src[i];
    float p = expf(leaky(as_[src] + adv) - m);
    s += p; acc += h3[src] * p;
  }
  #pragma unroll
  for (int off = 32; off; off >>= 1){ s += __shfl_xor(s, off); acc += __shfl_xor(acc, off); }
  if (j == 0) out[node] = acc / s + b3[0];
}

// ---------------- launch ----------------
extern "C" void kernel_launch(void* const* d_in, const int* in_sizes, int n_in,
                              void* d_out, int out_size, void* d_ws, size_t ws_size,
                              hipStream_t stream){
  const float* x   = (const float*)d_in[0];
  const int*   ei  = (const int*)  d_in[1];
  const float* W1  = (const float*)d_in[2];
  const float* as1 = (const float*)d_in[3];
  const float* ad1 = (const float*)d_in[4];
  const float* b1  = (const float*)d_in[5];
  const float* W2  = (const float*)d_in[6];
  const float* as2 = (const float*)d_in[7];
  const float* ad2 = (const float*)d_in[8];
  const float* b2  = (const float*)d_in[9];
  const float* W3  = (const float*)d_in[10];
  const float* as3 = (const float*)d_in[11];
  const float* ad3 = (const float*)d_in[12];
  const float* b3  = (const float*)d_in[13];

  const int N    = in_sizes[0];       // IN_C = 1
  const int Eg   = in_sizes[1] / 2;
  const int Etot = Eg + N;
  const int* esrc = ei;
  const int* edst = ei + Eg;

  // workspace carve (16B-aligned chunks)
  char* w = (char*)d_ws;
  auto carve = [&](size_t bytes)->char*{
    char* p = w; w += (bytes + 15) & ~size_t(15); return p;
  };
  float* hbuf   = (float*)carve((size_t)N * 128 * 4);
  float* actA   = (float*)carve((size_t)N * 128 * 4);
  float* asb    = (float*)carve((size_t)N * 4 * 4);
  float* adb    = (float*)carve((size_t)N * 4 * 4);
  float* h3b    = (float*)carve((size_t)N * 4);
  float* as3b   = (float*)carve((size_t)N * 4);
  float* ad3b   = (float*)carve((size_t)N * 4);
  int*   deg    = (int*)  carve((size_t)N * 4);
  int*   rowp   = (int*)  carve((size_t)(N + 1) * 4);
  int*   cursor = (int*)  carve((size_t)N * 4);
  int*   csr_src= (int*)  carve((size_t)Etot * 4);
  float* dAdD   = (float*)carve(8 * 4);

  const int B = 256;
  auto cdiv = [](int a, int b){ return (a + b - 1) / b; };

  // ---- CSR build (shared by all 3 layers) ----
  fill_i32_k<<<cdiv(N, B), B, 0, stream>>>(deg, 0, N);
  hist_k<<<cdiv(Etot, B), B, 0, stream>>>(edst, deg, Eg, Etot);
  scan_k<<<1, 1024, 0, stream>>>(deg, rowp, cursor, N);
  scatter_k<<<cdiv(Etot, B), B, 0, stream>>>(esrc, edst, cursor, csr_src, Eg, Etot);

  // ---- layer 1 ----
  dots1_k<<<1, 128, 0, stream>>>(W1, as1, ad1, dAdD);
  transform1_k<<<cdiv(N * 32, B), B, 0, stream>>>(x, W1, dAdD, (float4*)hbuf, asb, adb, N);
  node_aggr_k<true><<<cdiv(N, 2), B, 0, stream>>>(rowp, csr_src, asb, adb, hbuf, b1, actA, N);

  // ---- layer 2 ----
  gemm2_k<<<cdiv(N, 64), B, 0, stream>>>(actA, W2, as2, ad2, hbuf, asb, adb, N);
  node_aggr_k<true><<<cdiv(N, 2), B, 0, stream>>>(rowp, csr_src, asb, adb, hbuf, b2, actA, N);

  // ---- layer 3 (H=1, C=1) ----
  transform3_k<<<cdiv(N, 8), B, 0, stream>>>(actA, W3, as3, ad3, h3b, as3b, ad3b, N);
  node_aggr3_k<<<cdiv(N, 4), B, 0, stream>>>(rowp, csr_src, as3b, ad3b, h3b, b3, (float*)d_out, N);
}

// Round 3
// 497.404 us; speedup vs baseline: 3.9330x; 1.5390x over previous
//
#include <hip/hip_runtime.h>
#include <math.h>

#define NEG_SLOPE 0.2f

static __device__ __forceinline__ float leaky(float v){ return v > 0.f ? v : NEG_SLOPE * v; }

// ---------------- CSR build ----------------
__global__ void fill_i32_k(int* __restrict__ p, int v, int n){
  int i = blockIdx.x * blockDim.x + threadIdx.x;
  if (i < n) p[i] = v;
}

__global__ void hist_k(const int* __restrict__ edst, int* __restrict__ deg, int Eg, int Etot){
  int e = blockIdx.x * blockDim.x + threadIdx.x;
  if (e >= Etot) return;
  int d = (e < Eg) ? edst[e] : (e - Eg);
  atomicAdd(&deg[d], 1);
}

// single block, 1024 threads: exclusive scan of deg[N] -> row[N+1], copy to cursor
__global__ void __launch_bounds__(1024) scan_k(const int* __restrict__ deg,
                                               int* __restrict__ row, int* __restrict__ cursor, int N){
  __shared__ int part[1024];
  const int t = threadIdx.x;
  const int per = (N + 1023) / 1024;
  const int base = t * per;
  int sum = 0;
  for (int i = 0; i < per; ++i){ int idx = base + i; if (idx < N) sum += deg[idx]; }
  part[t] = sum; __syncthreads();
  for (int off = 1; off < 1024; off <<= 1){
    int v = (t >= off) ? part[t - off] : 0;
    __syncthreads();
    part[t] += v;
    __syncthreads();
  }
  int run = (t == 0) ? 0 : part[t - 1];
  for (int i = 0; i < per; ++i){
    int idx = base + i;
    if (idx < N){ row[idx] = run; cursor[idx] = run; run += deg[idx]; }
  }
  if (t == 1023) row[N] = part[1023];
}

__global__ void scatter_k(const int* __restrict__ esrc, const int* __restrict__ edst,
                          int* __restrict__ cursor, int* __restrict__ csr_src, int Eg, int Etot){
  int e = blockIdx.x * blockDim.x + threadIdx.x;
  if (e >= Etot) return;
  int s, d;
  if (e < Eg){ s = esrc[e]; d = edst[e]; } else { s = d = e - Eg; }
  int pos = atomicAdd(&cursor[d], 1);
  csr_src[pos] = s;
}

// ---------------- layer 1 (Fin = 1) ----------------
__global__ void dots1_k(const float* __restrict__ W1, const float* __restrict__ a_s,
                        const float* __restrict__ a_d, float* __restrict__ dAdD){
  int t = threadIdx.x;
  float ps = W1[t] * a_s[t];
  float pd = W1[t] * a_d[t];
  #pragma unroll
  for (int off = 16; off; off >>= 1){
    ps += __shfl_xor(ps, off, 32);
    pd += __shfl_xor(pd, off, 32);
  }
  if ((t & 31) == 0){ dAdD[t >> 5] = ps; dAdD[4 + (t >> 5)] = pd; }
}

__global__ void transform1_k(const float* __restrict__ x, const float* __restrict__ W1,
                             const float* __restrict__ dAdD,
                             float4* __restrict__ h4, float* __restrict__ as_, float* __restrict__ ad_,
                             int N){
  int idx = blockIdx.x * blockDim.x + threadIdx.x;   // over N*32
  if (idx >= N * 32) return;
  int n = idx >> 5, c4 = idx & 31;
  float xv = x[n];
  float4 w = ((const float4*)W1)[c4];
  float4 o; o.x = xv * w.x; o.y = xv * w.y; o.z = xv * w.z; o.w = xv * w.w;
  h4[idx] = o;
  if (c4 < 4){
    as_[n * 4 + c4] = xv * dAdD[c4];
    ad_[n * 4 + c4] = xv * dAdD[4 + c4];
  }
}

// ---------------- per-node softmax + aggregate (layers 1,2) ----------------
// 32 threads per node (8 nodes / 256-block). lane j owns channels 4j..4j+3
// (head = j>>3). Edge loop hand-unrolled x4 with loads hoisted.
template<bool DO_ELU>
__global__ void __launch_bounds__(256) node_aggr_k(const int* __restrict__ row, const int* __restrict__ csr_src,
                                                   const float* __restrict__ as_, const float* __restrict__ ad_,
                                                   const float4* __restrict__ h4, const float4* __restrict__ bias4,
                                                   float4* __restrict__ out4, int N){
  int node = blockIdx.x * 8 + (threadIdx.x >> 5);
  if (node >= N) return;
  const int j  = threadIdx.x & 31;
  const int hd = j >> 3;
  const int q  = j & 7;
  const int start = row[node], end = row[node + 1];
  const float adv = ad_[node * 4 + hd];

  // per-head max: the 8 lanes of this head stride the edge list by 8
  float m = -INFINITY;
  for (int i = start + q; i < end; i += 8){
    int src = csr_src[i];
    m = fmaxf(m, leaky(as_[src * 4 + hd] + adv));
  }
  #pragma unroll
  for (int off = 4; off; off >>= 1) m = fmaxf(m, __shfl_xor(m, off, 32));

  // serial edge loop, unrolled x4, all lanes iterate all edges
  float s = 0.f;
  float4 acc = make_float4(0.f, 0.f, 0.f, 0.f);
  int i = start;
  const int n4 = start + ((end - start) & ~3);
  for (; i < n4; i += 4){
    int s0 = csr_src[i], s1 = csr_src[i+1], s2 = csr_src[i+2], s3 = csr_src[i+3];
    float a0 = as_[s0*4 + hd], a1 = as_[s1*4 + hd], a2 = as_[s2*4 + hd], a3 = as_[s3*4 + hd];
    float4 h0 = h4[(size_t)s0*32 + j];
    float4 h1 = h4[(size_t)s1*32 + j];
    float4 h2 = h4[(size_t)s2*32 + j];
    float4 h3 = h4[(size_t)s3*32 + j];
    float p0 = expf(leaky(a0 + adv) - m);
    float p1 = expf(leaky(a1 + adv) - m);
    float p2 = expf(leaky(a2 + adv) - m);
    float p3 = expf(leaky(a3 + adv) - m);
    s += (p0 + p1) + (p2 + p3);
    acc.x += h0.x*p0 + h1.x*p1 + h2.x*p2 + h3.x*p3;
    acc.y += h0.y*p0 + h1.y*p1 + h2.y*p2 + h3.y*p3;
    acc.z += h0.z*p0 + h1.z*p1 + h2.z*p2 + h3.z*p3;
    acc.w += h0.w*p0 + h1.w*p1 + h2.w*p2 + h3.w*p3;
  }
  for (; i < end; ++i){
    int src = csr_src[i];
    float p = expf(leaky(as_[src*4 + hd] + adv) - m);
    float4 hv = h4[(size_t)src*32 + j];
    s += p;
    acc.x += hv.x*p; acc.y += hv.y*p; acc.z += hv.z*p; acc.w += hv.w*p;
  }
  float inv = 1.f / s;
  float4 b = bias4[j];
  float4 v;
  v.x = acc.x * inv + b.x;
  v.y = acc.y * inv + b.y;
  v.z = acc.z * inv + b.z;
  v.w = acc.w * inv + b.w;
  if (DO_ELU){
    v.x = v.x > 0.f ? v.x : expm1f(v.x);
    v.y = v.y > 0.f ? v.y : expm1f(v.y);
    v.z = v.z > 0.f ? v.z : expm1f(v.z);
    v.w = v.w > 0.f ? v.w : expm1f(v.w);
  }
  out4[(size_t)node * 32 + j] = v;
}

// ---------------- layer 2 dense: h = A(Nx128) * W(128x128), alphas fused ----------------
// BM=64 BN=128 BK=16, double-buffered LDS, 256 threads, 4x8 per-thread tile.
__global__ void __launch_bounds__(256) gemm2_k(const float* __restrict__ A, const float* __restrict__ W,
                                               const float* __restrict__ a_s, const float* __restrict__ a_d,
                                               float* __restrict__ h, float* __restrict__ as_, float* __restrict__ ad_,
                                               int N){
  __shared__ float sA[2][16][68];    // [buf][k][row] transposed, padded
  __shared__ float sW[2][16][128];   // [buf][k][col]
  const int t = threadIdx.x;
  const int n0 = blockIdx.x * 64;
  const int tx = t & 15, ty = t >> 4;
  const int c0 = tx * 8, r0 = ty * 4;

  const int lr = t >> 2;         // 0..63: A row within tile
  const int lg = t & 3;          // A k-quad
  const int wk = t >> 5;         // 0..7: W k row
  const int wq = t & 31;         // W col-quad

  float4 ra, rw0, rw1;
  const int grA = n0 + lr;
  auto gload = [&](int k0){
    ra  = (grA < N) ? *(const float4*)&A[(size_t)grA * 128 + k0 + lg * 4] : make_float4(0.f,0.f,0.f,0.f);
    rw0 = *(const float4*)&W[(size_t)(k0 + wk) * 128 + wq * 4];
    rw1 = *(const float4*)&W[(size_t)(k0 + wk + 8) * 128 + wq * 4];
  };
  auto sstore = [&](int buf){
    sA[buf][lg*4 + 0][lr] = ra.x;
    sA[buf][lg*4 + 1][lr] = ra.y;
    sA[buf][lg*4 + 2][lr] = ra.z;
    sA[buf][lg*4 + 3][lr] = ra.w;
    *(float4*)&sW[buf][wk][wq*4]     = rw0;
    *(float4*)&sW[buf][wk + 8][wq*4] = rw1;
  };

  float acc[4][8];
  #pragma unroll
  for (int r = 0; r < 4; ++r)
    #pragma unroll
    for (int c = 0; c < 8; ++c) acc[r][c] = 0.f;

  gload(0); sstore(0); __syncthreads();

  #pragma unroll 1
  for (int tile = 0; tile < 8; ++tile){
    const int buf = tile & 1;
    if (tile < 7) gload((tile + 1) * 16);
    #pragma unroll
    for (int k = 0; k < 16; ++k){
      float4 aa = *(const float4*)&sA[buf][k][r0];
      float4 w0 = *(const float4*)&sW[buf][k][c0];
      float4 w1 = *(const float4*)&sW[buf][k][c0 + 4];
      float av[4] = {aa.x, aa.y, aa.z, aa.w};
      float wv[8] = {w0.x, w0.y, w0.z, w0.w, w1.x, w1.y, w1.z, w1.w};
      #pragma unroll
      for (int r = 0; r < 4; ++r)
        #pragma unroll
        for (int c = 0; c < 8; ++c) acc[r][c] += av[r] * wv[c];
    }
    if (tile < 7){ sstore(1 - buf); __syncthreads(); }
  }

  // epilogue: h writes + fused alpha dots (reduce over the 4 col-groups per head)
  float asv[8], adv[8];
  #pragma unroll
  for (int c = 0; c < 8; ++c){ asv[c] = a_s[c0 + c]; adv[c] = a_d[c0 + c]; }

  #pragma unroll
  for (int r = 0; r < 4; ++r){
    int n = n0 + r0 + r;
    if (n >= N) continue;
    float4 o0 = make_float4(acc[r][0], acc[r][1], acc[r][2], acc[r][3]);
    float4 o1 = make_float4(acc[r][4], acc[r][5], acc[r][6], acc[r][7]);
    float4* hp = (float4*)&h[(size_t)n * 128 + c0];
    hp[0] = o0; hp[1] = o1;
    float ps = 0.f, pd = 0.f;
    #pragma unroll
    for (int c = 0; c < 8; ++c){ ps += acc[r][c] * asv[c]; pd += acc[r][c] * adv[c]; }
    ps += __shfl_xor(ps, 1); ps += __shfl_xor(ps, 2);
    pd += __shfl_xor(pd, 1); pd += __shfl_xor(pd, 2);
    if ((tx & 3) == 0){
      as_[n * 4 + (tx >> 2)] = ps;
      ad_[n * 4 + (tx >> 2)] = pd;
    }
  }
}

// ---------------- layer 3 ----------------
__global__ void __launch_bounds__(256) transform3_k(const float* __restrict__ A, const float* __restrict__ W3,
                                                    const float* __restrict__ a_s3, const float* __restrict__ a_d3,
                                                    float* __restrict__ h3, float* __restrict__ as_, float* __restrict__ ad_,
                                                    int N){
  int node = blockIdx.x * 8 + (threadIdx.x >> 5);
  if (node >= N) return;
  int j = threadIdx.x & 31;
  float4 a = ((const float4*)A)[(size_t)node * 32 + j];
  float4 w = ((const float4*)W3)[j];
  float acc = a.x * w.x + a.y * w.y + a.z * w.z + a.w * w.w;
  #pragma unroll
  for (int off = 16; off; off >>= 1) acc += __shfl_xor(acc, off, 32);
  if (j == 0){
    h3[node]  = acc;
    as_[node] = acc * a_s3[0];
    ad_[node] = acc * a_d3[0];
  }
}

__global__ void __launch_bounds__(256) node_aggr3_k(const int* __restrict__ row, const int* __restrict__ csr_src,
                                                    const float* __restrict__ as_, const float* __restrict__ ad_,
                                                    const float* __restrict__ h3, const float* __restrict__ b3,
                                                    float* __restrict__ out, int N){
  int node = blockIdx.x * 4 + (threadIdx.x >> 6);
  if (node >= N) return;
  int j = threadIdx.x & 63;
  int start = row[node], end = row[node + 1];
  float adv = ad_[node];
  float m = -INFINITY;
  for (int i = start + j; i < end; i += 64)
    m = fmaxf(m, leaky(as_[csr_src[i]] + adv));
  #pragma unroll
  for (int off = 32; off; off >>= 1) m = fmaxf(m, __shfl_xor(m, off));
  float s = 0.f, acc = 0.f;
  for (int i = start + j; i < end; i += 64){
    int src = csr_src[i];
    float p = expf(leaky(as_[src] + adv) - m);
    s += p; acc += h3[src] * p;
  }
  #pragma unroll
  for (int off = 32; off; off >>= 1){ s += __shfl_xor(s, off); acc += __shfl_xor(acc, off); }
  if (j == 0) out[node] = acc / s + b3[0];
}

// ---------------- launch ----------------
extern "C" void kernel_launch(void* const* d_in, const int* in_sizes, int n_in,
                              void* d_out, int out_size, void* d_ws, size_t ws_size,
                              hipStream_t stream){
  const float* x   = (const float*)d_in[0];
  const int*   ei  = (const int*)  d_in[1];
  const float* W1  = (const float*)d_in[2];
  const float* as1 = (const float*)d_in[3];
  const float* ad1 = (const float*)d_in[4];
  const float* b1  = (const float*)d_in[5];
  const float* W2  = (const float*)d_in[6];
  const float* as2 = (const float*)d_in[7];
  const float* ad2 = (const float*)d_in[8];
  const float* b2  = (const float*)d_in[9];
  const float* W3  = (const float*)d_in[10];
  const float* as3 = (const float*)d_in[11];
  const float* ad3 = (const float*)d_in[12];
  const float* b3  = (const float*)d_in[13];

  const int N    = in_sizes[0];       // IN_C = 1
  const int Eg   = in_sizes[1] / 2;
  const int Etot = Eg + N;
  const int* esrc = ei;
  const int* edst = ei + Eg;

  char* w = (char*)d_ws;
  auto carve = [&](size_t bytes)->char*{
    char* p = w; w += (bytes + 15) & ~size_t(15); return p;
  };
  float* hbuf   = (float*)carve((size_t)N * 128 * 4);
  float* actA   = (float*)carve((size_t)N * 128 * 4);
  float* asb    = (float*)carve((size_t)N * 4 * 4);
  float* adb    = (float*)carve((size_t)N * 4 * 4);
  float* h3b    = (float*)carve((size_t)N * 4);
  float* as3b   = (float*)carve((size_t)N * 4);
  float* ad3b   = (float*)carve((size_t)N * 4);
  int*   deg    = (int*)  carve((size_t)N * 4);
  int*   rowp   = (int*)  carve((size_t)(N + 1) * 4);
  int*   cursor = (int*)  carve((size_t)N * 4);
  int*   csr_src= (int*)  carve((size_t)Etot * 4);
  float* dAdD   = (float*)carve(8 * 4);

  const int B = 256;
  auto cdiv = [](int a, int b){ return (a + b - 1) / b; };

  // ---- CSR build (shared by all 3 layers) ----
  fill_i32_k<<<cdiv(N, B), B, 0, stream>>>(deg, 0, N);
  hist_k<<<cdiv(Etot, B), B, 0, stream>>>(edst, deg, Eg, Etot);
  scan_k<<<1, 1024, 0, stream>>>(deg, rowp, cursor, N);
  scatter_k<<<cdiv(Etot, B), B, 0, stream>>>(esrc, edst, cursor, csr_src, Eg, Etot);

  // ---- layer 1 ----
  dots1_k<<<1, 128, 0, stream>>>(W1, as1, ad1, dAdD);
  transform1_k<<<cdiv(N * 32, B), B, 0, stream>>>(x, W1, dAdD, (float4*)hbuf, asb, adb, N);
  node_aggr_k<true><<<cdiv(N, 8), B, 0, stream>>>(rowp, csr_src, asb, adb,
                                                  (const float4*)hbuf, (const float4*)b1,
                                                  (float4*)actA, N);

  // ---- layer 2 ----
  gemm2_k<<<cdiv(N, 64), B, 0, stream>>>(actA, W2, as2, ad2, hbuf, asb, adb, N);
  node_aggr_k<true><<<cdiv(N, 8), B, 0, stream>>>(rowp, csr_src, asb, adb,
                                                  (const float4*)hbuf, (const float4*)b2,
                                                  (float4*)actA, N);

  // ---- layer 3 (H=1, C=1) ----
  transform3_k<<<cdiv(N, 8), B, 0, stream>>>(actA, W3, as3, ad3, h3b, as3b, ad3b, N);
  node_aggr3_k<<<cdiv(N, 4), B, 0, stream>>>(rowp, csr_src, as3b, ad3b, h3b, b3, (float*)d_out, N);
}

// Round 4
// 384.263 us; speedup vs baseline: 5.0910x; 1.2944x over previous
//
#include <hip/hip_runtime.h>
#include <math.h>

#define NEG_SLOPE 0.2f

static __device__ __forceinline__ float leaky(float v){ return v > 0.f ? v : NEG_SLOPE * v; }

// ---------------- CSR build ----------------
__global__ void fill_i32_k(int* __restrict__ p, int v, int n){
  int i = blockIdx.x * blockDim.x + threadIdx.x;
  if (i < n) p[i] = v;
}

__global__ void hist_k(const int* __restrict__ edst, int* __restrict__ deg, int Eg, int Etot){
  int e = blockIdx.x * blockDim.x + threadIdx.x;
  if (e >= Etot) return;
  int d = (e < Eg) ? edst[e] : (e - Eg);
  atomicAdd(&deg[d], 1);
}

// --- multi-block exclusive scan over deg[N] -> row[N+1] (+cursor copy) ---
// A: per-block sums (2048 elems / 256-thread block)
__global__ void __launch_bounds__(256) scan_part_k(const int* __restrict__ deg,
                                                   int* __restrict__ bsum, int N){
  __shared__ int red[256];
  const int t = threadIdx.x;
  const int base = blockIdx.x * 2048;
  int sum = 0;
  #pragma unroll
  for (int i = 0; i < 8; ++i){
    int idx = base + t + i * 256;
    if (idx < N) sum += deg[idx];
  }
  red[t] = sum; __syncthreads();
  #pragma unroll
  for (int d = 128; d; d >>= 1){
    if (t < d) red[t] += red[t + d];
    __syncthreads();
  }
  if (t == 0) bsum[blockIdx.x] = red[0];
}

// B: one wave scans the block sums (nb <= 64), writes exclusive offsets + row[N]
__global__ void scan_tops_k(const int* __restrict__ bsum, int* __restrict__ boff,
                            int* __restrict__ row, int nb, int N){
  int t = threadIdx.x;   // 64 threads
  int v = (t < nb) ? bsum[t] : 0;
  int orig = v;
  #pragma unroll
  for (int off = 1; off < 64; off <<= 1){
    int u = __shfl_up(v, off, 64);
    if (t >= off) v += u;
  }
  if (t < nb) boff[t] = v - orig;
  if (t == nb - 1) row[N] = v;
}

// C: per-block local exclusive scan + global offset, write row & cursor
__global__ void __launch_bounds__(256) scan_write_k(const int* __restrict__ deg,
                                                    const int* __restrict__ boff,
                                                    int* __restrict__ row, int* __restrict__ cursor, int N){
  __shared__ int sdeg[2048];
  __shared__ int tsum[256];
  const int t = threadIdx.x;
  const int base = blockIdx.x * 2048;
  for (int i = t; i < 2048; i += 256){
    int idx = base + i;
    sdeg[i] = (idx < N) ? deg[idx] : 0;
  }
  __syncthreads();
  const int off = t * 8;
  int sum = 0;
  #pragma unroll
  for (int i = 0; i < 8; ++i) sum += sdeg[off + i];
  tsum[t] = sum; __syncthreads();
  for (int d = 1; d < 256; d <<= 1){
    int v = (t >= d) ? tsum[t - d] : 0;
    __syncthreads();
    tsum[t] += v;
    __syncthreads();
  }
  int run = boff[blockIdx.x] + ((t == 0) ? 0 : tsum[t - 1]);
  #pragma unroll
  for (int i = 0; i < 8; ++i){
    int idx = base + off + i;
    if (idx < N){ row[idx] = run; cursor[idx] = run; run += sdeg[off + i]; }
  }
}

__global__ void scatter_k(const int* __restrict__ esrc, const int* __restrict__ edst,
                          int* __restrict__ cursor, int* __restrict__ csr_src, int Eg, int Etot){
  int e = blockIdx.x * blockDim.x + threadIdx.x;
  if (e >= Etot) return;
  int s, d;
  if (e < Eg){ s = esrc[e]; d = edst[e]; } else { s = d = e - Eg; }
  int pos = atomicAdd(&cursor[d], 1);
  csr_src[pos] = s;
}

// ---------------- layer 1 (Fin = 1) ----------------
__global__ void dots1_k(const float* __restrict__ W1, const float* __restrict__ a_s,
                        const float* __restrict__ a_d, float* __restrict__ dAdD){
  int t = threadIdx.x;
  float ps = W1[t] * a_s[t];
  float pd = W1[t] * a_d[t];
  #pragma unroll
  for (int off = 16; off; off >>= 1){
    ps += __shfl_xor(ps, off, 32);
    pd += __shfl_xor(pd, off, 32);
  }
  if ((t & 31) == 0){ dAdD[t >> 5] = ps; dAdD[4 + (t >> 5)] = pd; }
}

__global__ void transform1_k(const float* __restrict__ x, const float* __restrict__ W1,
                             const float* __restrict__ dAdD,
                             float4* __restrict__ h4, float* __restrict__ as_, float* __restrict__ ad_,
                             int N){
  int idx = blockIdx.x * blockDim.x + threadIdx.x;   // over N*32
  if (idx >= N * 32) return;
  int n = idx >> 5, c4 = idx & 31;
  float xv = x[n];
  float4 w = ((const float4*)W1)[c4];
  float4 o; o.x = xv * w.x; o.y = xv * w.y; o.z = xv * w.z; o.w = xv * w.w;
  h4[idx] = o;
  if (c4 < 4){
    as_[n * 4 + c4] = xv * dAdD[c4];
    ad_[n * 4 + c4] = xv * dAdD[4 + c4];
  }
}

// ---------------- per-node online-softmax aggregate (layers 1,2) ----------------
// 32 threads per node (8 nodes / 256-block). lane j owns channels 4j..4j+3
// (head = j>>3). Single edge pass, flash-style running (m,s,acc) rescale.
template<bool DO_ELU>
__global__ void __launch_bounds__(256) node_aggr_k(const int* __restrict__ row, const int* __restrict__ csr_src,
                                                   const float* __restrict__ as_, const float* __restrict__ ad_,
                                                   const float4* __restrict__ h4, const float4* __restrict__ bias4,
                                                   float4* __restrict__ out4, int N){
  int node = blockIdx.x * 8 + (threadIdx.x >> 5);
  if (node >= N) return;
  const int j  = threadIdx.x & 31;
  const int hd = j >> 3;
  const int start = row[node], end = row[node + 1];
  const float adv = ad_[node * 4 + hd];

  float m = -INFINITY, s = 0.f;
  float4 acc = make_float4(0.f, 0.f, 0.f, 0.f);
  int i = start;
  const int n4 = start + ((end - start) & ~3);
  for (; i < n4; i += 4){
    int s0 = csr_src[i], s1 = csr_src[i+1], s2 = csr_src[i+2], s3 = csr_src[i+3];
    float4 h0 = h4[(size_t)s0*32 + j];
    float4 h1 = h4[(size_t)s1*32 + j];
    float4 h2 = h4[(size_t)s2*32 + j];
    float4 h3 = h4[(size_t)s3*32 + j];
    float e0 = leaky(as_[s0*4 + hd] + adv);
    float e1 = leaky(as_[s1*4 + hd] + adv);
    float e2 = leaky(as_[s2*4 + hd] + adv);
    float e3 = leaky(as_[s3*4 + hd] + adv);
    float nm = fmaxf(fmaxf(fmaxf(e0, e1), fmaxf(e2, e3)), m);
    float sc = expf(m - nm);
    float p0 = expf(e0 - nm);
    float p1 = expf(e1 - nm);
    float p2 = expf(e2 - nm);
    float p3 = expf(e3 - nm);
    s = s * sc + (p0 + p1) + (p2 + p3);
    acc.x = acc.x * sc + h0.x*p0 + h1.x*p1 + h2.x*p2 + h3.x*p3;
    acc.y = acc.y * sc + h0.y*p0 + h1.y*p1 + h2.y*p2 + h3.y*p3;
    acc.z = acc.z * sc + h0.z*p0 + h1.z*p1 + h2.z*p2 + h3.z*p3;
    acc.w = acc.w * sc + h0.w*p0 + h1.w*p1 + h2.w*p2 + h3.w*p3;
    m = nm;
  }
  for (; i < end; ++i){
    int src = csr_src[i];
    float e = leaky(as_[src*4 + hd] + adv);
    float4 hv = h4[(size_t)src*32 + j];
    float nm = fmaxf(m, e);
    float sc = expf(m - nm);
    float p  = expf(e - nm);
    s = s * sc + p;
    acc.x = acc.x * sc + hv.x*p;
    acc.y = acc.y * sc + hv.y*p;
    acc.z = acc.z * sc + hv.z*p;
    acc.w = acc.w * sc + hv.w*p;
    m = nm;
  }
  float inv = 1.f / s;
  float4 b = bias4[j];
  float4 v;
  v.x = acc.x * inv + b.x;
  v.y = acc.y * inv + b.y;
  v.z = acc.z * inv + b.z;
  v.w = acc.w * inv + b.w;
  if (DO_ELU){
    v.x = v.x > 0.f ? v.x : expm1f(v.x);
    v.y = v.y > 0.f ? v.y : expm1f(v.y);
    v.z = v.z > 0.f ? v.z : expm1f(v.z);
    v.w = v.w > 0.f ? v.w : expm1f(v.w);
  }
  out4[(size_t)node * 32 + j] = v;
}

// ---------------- layer 2 dense: h = A(Nx128) * W(128x128), alphas fused ----------------
__global__ void __launch_bounds__(256) gemm2_k(const float* __restrict__ A, const float* __restrict__ W,
                                               const float* __restrict__ a_s, const float* __restrict__ a_d,
                                               float* __restrict__ h, float* __restrict__ as_, float* __restrict__ ad_,
                                               int N){
  __shared__ float sA[2][16][68];    // [buf][k][row] transposed, padded
  __shared__ float sW[2][16][128];   // [buf][k][col]
  const int t = threadIdx.x;
  const int n0 = blockIdx.x * 64;
  const int tx = t & 15, ty = t >> 4;
  const int c0 = tx * 8, r0 = ty * 4;

  const int lr = t >> 2;         // 0..63: A row within tile
  const int lg = t & 3;          // A k-quad
  const int wk = t >> 5;         // 0..7: W k row
  const int wq = t & 31;         // W col-quad

  float4 ra, rw0, rw1;
  const int grA = n0 + lr;
  auto gload = [&](int k0){
    ra  = (grA < N) ? *(const float4*)&A[(size_t)grA * 128 + k0 + lg * 4] : make_float4(0.f,0.f,0.f,0.f);
    rw0 = *(const float4*)&W[(size_t)(k0 + wk) * 128 + wq * 4];
    rw1 = *(const float4*)&W[(size_t)(k0 + wk + 8) * 128 + wq * 4];
  };
  auto sstore = [&](int buf){
    sA[buf][lg*4 + 0][lr] = ra.x;
    sA[buf][lg*4 + 1][lr] = ra.y;
    sA[buf][lg*4 + 2][lr] = ra.z;
    sA[buf][lg*4 + 3][lr] = ra.w;
    *(float4*)&sW[buf][wk][wq*4]     = rw0;
    *(float4*)&sW[buf][wk + 8][wq*4] = rw1;
  };

  float acc[4][8];
  #pragma unroll
  for (int r = 0; r < 4; ++r)
    #pragma unroll
    for (int c = 0; c < 8; ++c) acc[r][c] = 0.f;

  gload(0); sstore(0); __syncthreads();

  #pragma unroll 1
  for (int tile = 0; tile < 8; ++tile){
    const int buf = tile & 1;
    if (tile < 7) gload((tile + 1) * 16);
    #pragma unroll
    for (int k = 0; k < 16; ++k){
      float4 aa = *(const float4*)&sA[buf][k][r0];
      float4 w0 = *(const float4*)&sW[buf][k][c0];
      float4 w1 = *(const float4*)&sW[buf][k][c0 + 4];
      float av[4] = {aa.x, aa.y, aa.z, aa.w};
      float wv[8] = {w0.x, w0.y, w0.z, w0.w, w1.x, w1.y, w1.z, w1.w};
      #pragma unroll
      for (int r = 0; r < 4; ++r)
        #pragma unroll
        for (int c = 0; c < 8; ++c) acc[r][c] += av[r] * wv[c];
    }
    if (tile < 7){ sstore(1 - buf); __syncthreads(); }
  }

  float asv[8], adv[8];
  #pragma unroll
  for (int c = 0; c < 8; ++c){ asv[c] = a_s[c0 + c]; adv[c] = a_d[c0 + c]; }

  #pragma unroll
  for (int r = 0; r < 4; ++r){
    int n = n0 + r0 + r;
    if (n >= N) continue;
    float4 o0 = make_float4(acc[r][0], acc[r][1], acc[r][2], acc[r][3]);
    float4 o1 = make_float4(acc[r][4], acc[r][5], acc[r][6], acc[r][7]);
    float4* hp = (float4*)&h[(size_t)n * 128 + c0];
    hp[0] = o0; hp[1] = o1;
    float ps = 0.f, pd = 0.f;
    #pragma unroll
    for (int c = 0; c < 8; ++c){ ps += acc[r][c] * asv[c]; pd += acc[r][c] * adv[c]; }
    ps += __shfl_xor(ps, 1); ps += __shfl_xor(ps, 2);
    pd += __shfl_xor(pd, 1); pd += __shfl_xor(pd, 2);
    if ((tx & 3) == 0){
      as_[n * 4 + (tx >> 2)] = ps;
      ad_[n * 4 + (tx >> 2)] = pd;
    }
  }
}

// ---------------- layer 3 ----------------
__global__ void __launch_bounds__(256) transform3_k(const float* __restrict__ A, const float* __restrict__ W3,
                                                    const float* __restrict__ a_s3, const float* __restrict__ a_d3,
                                                    float* __restrict__ h3, float* __restrict__ as_, float* __restrict__ ad_,
                                                    int N){
  int node = blockIdx.x * 8 + (threadIdx.x >> 5);
  if (node >= N) return;
  int j = threadIdx.x & 31;
  float4 a = ((const float4*)A)[(size_t)node * 32 + j];
  float4 w = ((const float4*)W3)[j];
  float acc = a.x * w.x + a.y * w.y + a.z * w.z + a.w * w.w;
  #pragma unroll
  for (int off = 16; off; off >>= 1) acc += __shfl_xor(acc, off, 32);
  if (j == 0){
    h3[node]  = acc;
    as_[node] = acc * a_s3[0];
    ad_[node] = acc * a_d3[0];
  }
}

__global__ void __launch_bounds__(256) node_aggr3_k(const int* __restrict__ row, const int* __restrict__ csr_src,
                                                    const float* __restrict__ as_, const float* __restrict__ ad_,
                                                    const float* __restrict__ h3, const float* __restrict__ b3,
                                                    float* __restrict__ out, int N){
  int node = blockIdx.x * 4 + (threadIdx.x >> 6);
  if (node >= N) return;
  int j = threadIdx.x & 63;
  int start = row[node], end = row[node + 1];
  float adv = ad_[node];
  float m = -INFINITY;
  for (int i = start + j; i < end; i += 64)
    m = fmaxf(m, leaky(as_[csr_src[i]] + adv));
  #pragma unroll
  for (int off = 32; off; off >>= 1) m = fmaxf(m, __shfl_xor(m, off));
  float s = 0.f, acc = 0.f;
  for (int i = start + j; i < end; i += 64){
    int src = csr_src[i];
    float p = expf(leaky(as_[src] + adv) - m);
    s += p; acc += h3[src] * p;
  }
  #pragma unroll
  for (int off = 32; off; off >>= 1){ s += __shfl_xor(s, off); acc += __shfl_xor(acc, off); }
  if (j == 0) out[node] = acc / s + b3[0];
}

// ---------------- launch ----------------
extern "C" void kernel_launch(void* const* d_in, const int* in_sizes, int n_in,
                              void* d_out, int out_size, void* d_ws, size_t ws_size,
                              hipStream_t stream){
  const float* x   = (const float*)d_in[0];
  const int*   ei  = (const int*)  d_in[1];
  const float* W1  = (const float*)d_in[2];
  const float* as1 = (const float*)d_in[3];
  const float* ad1 = (const float*)d_in[4];
  const float* b1  = (const float*)d_in[5];
  const float* W2  = (const float*)d_in[6];
  const float* as2 = (const float*)d_in[7];
  const float* ad2 = (const float*)d_in[8];
  const float* b2  = (const float*)d_in[9];
  const float* W3  = (const float*)d_in[10];
  const float* as3 = (const float*)d_in[11];
  const float* ad3 = (const float*)d_in[12];
  const float* b3  = (const float*)d_in[13];

  const int N    = in_sizes[0];       // IN_C = 1
  const int Eg   = in_sizes[1] / 2;
  const int Etot = Eg + N;
  const int* esrc = ei;
  const int* edst = ei + Eg;

  char* w = (char*)d_ws;
  auto carve = [&](size_t bytes)->char*{
    char* p = w; w += (bytes + 15) & ~size_t(15); return p;
  };
  float* hbuf   = (float*)carve((size_t)N * 128 * 4);
  float* actA   = (float*)carve((size_t)N * 128 * 4);
  float* asb    = (float*)carve((size_t)N * 4 * 4);
  float* adb    = (float*)carve((size_t)N * 4 * 4);
  float* h3b    = (float*)carve((size_t)N * 4);
  float* as3b   = (float*)carve((size_t)N * 4);
  float* ad3b   = (float*)carve((size_t)N * 4);
  int*   deg    = (int*)  carve((size_t)N * 4);
  int*   rowp   = (int*)  carve((size_t)(N + 1) * 4);
  int*   cursor = (int*)  carve((size_t)N * 4);
  int*   csr_src= (int*)  carve((size_t)Etot * 4);
  float* dAdD   = (float*)carve(8 * 4);
  int*   bsum   = (int*)  carve(64 * 4);
  int*   boff   = (int*)  carve(64 * 4);

  const int B = 256;
  auto cdiv = [](int a, int b){ return (a + b - 1) / b; };
  const int nb = cdiv(N, 2048);   // 25 for N=50000 (must be <= 64)

  // ---- CSR build (shared by all 3 layers) ----
  fill_i32_k<<<cdiv(N, B), B, 0, stream>>>(deg, 0, N);
  hist_k<<<cdiv(Etot, B), B, 0, stream>>>(edst, deg, Eg, Etot);
  scan_part_k<<<nb, B, 0, stream>>>(deg, bsum, N);
  scan_tops_k<<<1, 64, 0, stream>>>(bsum, boff, rowp, nb, N);
  scan_write_k<<<nb, B, 0, stream>>>(deg, boff, rowp, cursor, N);
  scatter_k<<<cdiv(Etot, B), B, 0, stream>>>(esrc, edst, cursor, csr_src, Eg, Etot);

  // ---- layer 1 ----
  dots1_k<<<1, 128, 0, stream>>>(W1, as1, ad1, dAdD);
  transform1_k<<<cdiv(N * 32, B), B, 0, stream>>>(x, W1, dAdD, (float4*)hbuf, asb, adb, N);
  node_aggr_k<true><<<cdiv(N, 8), B, 0, stream>>>(rowp, csr_src, asb, adb,
                                                  (const float4*)hbuf, (const float4*)b1,
                                                  (float4*)actA, N);

  // ---- layer 2 ----
  gemm2_k<<<cdiv(N, 64), B, 0, stream>>>(actA, W2, as2, ad2, hbuf, asb, adb, N);
  node_aggr_k<true><<<cdiv(N, 8), B, 0, stream>>>(rowp, csr_src, asb, adb,
                                                  (const float4*)hbuf, (const float4*)b2,
                                                  (float4*)actA, N);

  // ---- layer 3 (H=1, C=1) ----
  transform3_k<<<cdiv(N, 8), B, 0, stream>>>(actA, W3, as3, ad3, h3b, as3b, ad3b, N);
  node_aggr3_k<<<cdiv(N, 4), B, 0, stream>>>(rowp, csr_src, as3b, ad3b, h3b, b3, (float*)d_out, N);
}

// Round 5
// 320.337 us; speedup vs baseline: 6.1070x; 1.1996x over previous
//
#include <hip/hip_runtime.h>
#include <math.h>

#define NEG_SLOPE 0.2f

static __device__ __forceinline__ float leaky(float v){ return v > 0.f ? v : NEG_SLOPE * v; }

// ---------------- CSR build ----------------
__global__ void fill_i32_k(int* __restrict__ p, int v, int n){
  int i = blockIdx.x * blockDim.x + threadIdx.x;
  if (i < n) p[i] = v;
}

__global__ void hist_k(const int* __restrict__ edst, int* __restrict__ deg, int Eg, int Etot){
  int e = blockIdx.x * blockDim.x + threadIdx.x;
  if (e >= Etot) return;
  int d = (e < Eg) ? edst[e] : (e - Eg);
  atomicAdd(&deg[d], 1);
}

// A: per-block sums (2048 elems / 256-thread block)
__global__ void __launch_bounds__(256) scan_part_k(const int* __restrict__ deg,
                                                   int* __restrict__ bsum, int N){
  __shared__ int red[256];
  const int t = threadIdx.x;
  const int base = blockIdx.x * 2048;
  int sum = 0;
  #pragma unroll
  for (int i = 0; i < 8; ++i){
    int idx = base + t + i * 256;
    if (idx < N) sum += deg[idx];
  }
  red[t] = sum; __syncthreads();
  #pragma unroll
  for (int d = 128; d; d >>= 1){
    if (t < d) red[t] += red[t + d];
    __syncthreads();
  }
  if (t == 0) bsum[blockIdx.x] = red[0];
}

// B: one wave scans the block sums (nb <= 64)
__global__ void scan_tops_k(const int* __restrict__ bsum, int* __restrict__ boff,
                            int* __restrict__ row, int nb, int N){
  int t = threadIdx.x;
  int v = (t < nb) ? bsum[t] : 0;
  int orig = v;
  #pragma unroll
  for (int off = 1; off < 64; off <<= 1){
    int u = __shfl_up(v, off, 64);
    if (t >= off) v += u;
  }
  if (t < nb) boff[t] = v - orig;
  if (t == nb - 1) row[N] = v;
}

// C: per-block local exclusive scan + global offset, write row & cursor
__global__ void __launch_bounds__(256) scan_write_k(const int* __restrict__ deg,
                                                    const int* __restrict__ boff,
                                                    int* __restrict__ row, int* __restrict__ cursor, int N){
  __shared__ int sdeg[2048];
  __shared__ int tsum[256];
  const int t = threadIdx.x;
  const int base = blockIdx.x * 2048;
  for (int i = t; i < 2048; i += 256){
    int idx = base + i;
    sdeg[i] = (idx < N) ? deg[idx] : 0;
  }
  __syncthreads();
  const int off = t * 8;
  int sum = 0;
  #pragma unroll
  for (int i = 0; i < 8; ++i) sum += sdeg[off + i];
  tsum[t] = sum; __syncthreads();
  for (int d = 1; d < 256; d <<= 1){
    int v = (t >= d) ? tsum[t - d] : 0;
    __syncthreads();
    tsum[t] += v;
    __syncthreads();
  }
  int run = boff[blockIdx.x] + ((t == 0) ? 0 : tsum[t - 1]);
  #pragma unroll
  for (int i = 0; i < 8; ++i){
    int idx = base + off + i;
    if (idx < N){ row[idx] = run; cursor[idx] = run; run += sdeg[off + i]; }
  }
}

__global__ void scatter_k(const int* __restrict__ esrc, const int* __restrict__ edst,
                          int* __restrict__ cursor, int* __restrict__ csr_src, int Eg, int Etot){
  int e = blockIdx.x * blockDim.x + threadIdx.x;
  if (e >= Etot) return;
  int s, d;
  if (e < Eg){ s = esrc[e]; d = edst[e]; } else { s = d = e - Eg; }
  int pos = atomicAdd(&cursor[d], 1);
  csr_src[pos] = s;
}

// ---------------- layer 1 (Fin = 1, rank-1) ----------------
// dA[h] = dot32(W1[h], a_s1[h]); dD likewise. one block of 128 threads.
__global__ void dots1_k(const float* __restrict__ W1, const float* __restrict__ a_s,
                        const float* __restrict__ a_d, float* __restrict__ dAdD){
  int t = threadIdx.x;
  float ps = W1[t] * a_s[t];
  float pd = W1[t] * a_d[t];
  #pragma unroll
  for (int off = 16; off; off >>= 1){
    ps += __shfl_xor(ps, off, 32);
    pd += __shfl_xor(pd, off, 32);
  }
  if ((t & 31) == 0){ dAdD[t >> 5] = ps; dAdD[4 + (t >> 5)] = pd; }
}

// Rank-1 layer-1 GAT: out[n][h*32+c] = W1[h*32+c] * (sum_e p_e x[src_e])/s_h + b1, ELU.
// 32 lanes per node; scalar x gather only; no max (shift-invariant softmax, bounded e).
__global__ void __launch_bounds__(256) node_aggr1_k(const int* __restrict__ row, const int* __restrict__ csr_src,
                                                    const float* __restrict__ x, const float* __restrict__ dAdD,
                                                    const float4* __restrict__ W1_4, const float4* __restrict__ b1_4,
                                                    float4* __restrict__ out4, int N){
  int node = blockIdx.x * 8 + (threadIdx.x >> 5);
  if (node >= N) return;
  const int j = threadIdx.x & 31;
  const int start = row[node], end = row[node + 1];
  const float xd = x[node];
  float dA0 = dAdD[0], dA1 = dAdD[1], dA2 = dAdD[2], dA3 = dAdD[3];
  float e0d = xd * dAdD[4], e1d = xd * dAdD[5], e2d = xd * dAdD[6], e3d = xd * dAdD[7];

  float s0 = 0.f, s1 = 0.f, s2 = 0.f, s3 = 0.f;
  float t0 = 0.f, t1 = 0.f, t2 = 0.f, t3 = 0.f;
  for (int i = start + j; i < end; i += 32){
    float xs = x[csr_src[i]];
    float p0 = __expf(leaky(xs * dA0 + e0d));
    float p1 = __expf(leaky(xs * dA1 + e1d));
    float p2 = __expf(leaky(xs * dA2 + e2d));
    float p3 = __expf(leaky(xs * dA3 + e3d));
    s0 += p0; s1 += p1; s2 += p2; s3 += p3;
    t0 += p0 * xs; t1 += p1 * xs; t2 += p2 * xs; t3 += p3 * xs;
  }
  #pragma unroll
  for (int off = 16; off; off >>= 1){
    s0 += __shfl_xor(s0, off, 32); t0 += __shfl_xor(t0, off, 32);
    s1 += __shfl_xor(s1, off, 32); t1 += __shfl_xor(t1, off, 32);
    s2 += __shfl_xor(s2, off, 32); t2 += __shfl_xor(t2, off, 32);
    s3 += __shfl_xor(s3, off, 32); t3 += __shfl_xor(t3, off, 32);
  }
  const int hd = j >> 3;
  float r = (hd == 0) ? t0 / s0 : (hd == 1) ? t1 / s1 : (hd == 2) ? t2 / s2 : t3 / s3;
  float4 w = W1_4[j], b = b1_4[j];
  float4 v;
  v.x = w.x * r + b.x;
  v.y = w.y * r + b.y;
  v.z = w.z * r + b.z;
  v.w = w.w * r + b.w;
  v.x = v.x > 0.f ? v.x : expm1f(v.x);
  v.y = v.y > 0.f ? v.y : expm1f(v.y);
  v.z = v.z > 0.f ? v.z : expm1f(v.z);
  v.w = v.w > 0.f ? v.w : expm1f(v.w);
  out4[(size_t)node * 32 + j] = v;
}

// ---------------- per-node aggregate, layer 2 ----------------
// 32 threads per node; lane j owns channels 4j..4j+3 (head = j>>3).
// Single pass, no max subtraction (bounded logits), __expf.
template<bool DO_ELU>
__global__ void __launch_bounds__(256) node_aggr_k(const int* __restrict__ row, const int* __restrict__ csr_src,
                                                   const float* __restrict__ as_, const float* __restrict__ ad_,
                                                   const float4* __restrict__ h4, const float4* __restrict__ bias4,
                                                   float4* __restrict__ out4, int N){
  int node = blockIdx.x * 8 + (threadIdx.x >> 5);
  if (node >= N) return;
  const int j  = threadIdx.x & 31;
  const int hd = j >> 3;
  const int start = row[node], end = row[node + 1];
  const float adv = ad_[node * 4 + hd];

  float s = 0.f;
  float4 acc = make_float4(0.f, 0.f, 0.f, 0.f);
  int i = start;
  const int n4 = start + ((end - start) & ~3);
  for (; i < n4; i += 4){
    int s0 = csr_src[i], s1 = csr_src[i+1], s2 = csr_src[i+2], s3 = csr_src[i+3];
    float a0 = as_[s0*4 + hd], a1 = as_[s1*4 + hd], a2 = as_[s2*4 + hd], a3 = as_[s3*4 + hd];
    float4 h0 = h4[(size_t)s0*32 + j];
    float4 h1 = h4[(size_t)s1*32 + j];
    float4 h2 = h4[(size_t)s2*32 + j];
    float4 h3 = h4[(size_t)s3*32 + j];
    float p0 = __expf(leaky(a0 + adv));
    float p1 = __expf(leaky(a1 + adv));
    float p2 = __expf(leaky(a2 + adv));
    float p3 = __expf(leaky(a3 + adv));
    s += (p0 + p1) + (p2 + p3);
    acc.x += h0.x*p0 + h1.x*p1 + h2.x*p2 + h3.x*p3;
    acc.y += h0.y*p0 + h1.y*p1 + h2.y*p2 + h3.y*p3;
    acc.z += h0.z*p0 + h1.z*p1 + h2.z*p2 + h3.z*p3;
    acc.w += h0.w*p0 + h1.w*p1 + h2.w*p2 + h3.w*p3;
  }
  for (; i < end; ++i){
    int src = csr_src[i];
    float p = __expf(leaky(as_[src*4 + hd] + adv));
    float4 hv = h4[(size_t)src*32 + j];
    s += p;
    acc.x += hv.x*p; acc.y += hv.y*p; acc.z += hv.z*p; acc.w += hv.w*p;
  }
  float inv = 1.f / s;
  float4 b = bias4[j];
  float4 v;
  v.x = acc.x * inv + b.x;
  v.y = acc.y * inv + b.y;
  v.z = acc.z * inv + b.z;
  v.w = acc.w * inv + b.w;
  if (DO_ELU){
    v.x = v.x > 0.f ? v.x : expm1f(v.x);
    v.y = v.y > 0.f ? v.y : expm1f(v.y);
    v.z = v.z > 0.f ? v.z : expm1f(v.z);
    v.w = v.w > 0.f ? v.w : expm1f(v.w);
  }
  out4[(size_t)node * 32 + j] = v;
}

// ---------------- layer 2 dense: h = A(Nx128) * W(128x128), alphas fused ----------------
__global__ void __launch_bounds__(256) gemm2_k(const float* __restrict__ A, const float* __restrict__ W,
                                               const float* __restrict__ a_s, const float* __restrict__ a_d,
                                               float* __restrict__ h, float* __restrict__ as_, float* __restrict__ ad_,
                                               int N){
  __shared__ float sA[2][16][68];    // [buf][k][row] transposed, padded
  __shared__ float sW[2][16][128];   // [buf][k][col]
  const int t = threadIdx.x;
  const int n0 = blockIdx.x * 64;
  const int tx = t & 15, ty = t >> 4;
  const int c0 = tx * 8, r0 = ty * 4;

  const int lr = t >> 2;         // 0..63: A row within tile
  const int lg = t & 3;          // A k-quad
  const int wk = t >> 5;         // 0..7: W k row
  const int wq = t & 31;         // W col-quad

  float4 ra, rw0, rw1;
  const int grA = n0 + lr;
  auto gload = [&](int k0){
    ra  = (grA < N) ? *(const float4*)&A[(size_t)grA * 128 + k0 + lg * 4] : make_float4(0.f,0.f,0.f,0.f);
    rw0 = *(const float4*)&W[(size_t)(k0 + wk) * 128 + wq * 4];
    rw1 = *(const float4*)&W[(size_t)(k0 + wk + 8) * 128 + wq * 4];
  };
  auto sstore = [&](int buf){
    sA[buf][lg*4 + 0][lr] = ra.x;
    sA[buf][lg*4 + 1][lr] = ra.y;
    sA[buf][lg*4 + 2][lr] = ra.z;
    sA[buf][lg*4 + 3][lr] = ra.w;
    *(float4*)&sW[buf][wk][wq*4]     = rw0;
    *(float4*)&sW[buf][wk + 8][wq*4] = rw1;
  };

  float acc[4][8];
  #pragma unroll
  for (int r = 0; r < 4; ++r)
    #pragma unroll
    for (int c = 0; c < 8; ++c) acc[r][c] = 0.f;

  gload(0); sstore(0); __syncthreads();

  #pragma unroll 1
  for (int tile = 0; tile < 8; ++tile){
    const int buf = tile & 1;
    if (tile < 7) gload((tile + 1) * 16);
    #pragma unroll
    for (int k = 0; k < 16; ++k){
      float4 aa = *(const float4*)&sA[buf][k][r0];
      float4 w0 = *(const float4*)&sW[buf][k][c0];
      float4 w1 = *(const float4*)&sW[buf][k][c0 + 4];
      float av[4] = {aa.x, aa.y, aa.z, aa.w};
      float wv[8] = {w0.x, w0.y, w0.z, w0.w, w1.x, w1.y, w1.z, w1.w};
      #pragma unroll
      for (int r = 0; r < 4; ++r)
        #pragma unroll
        for (int c = 0; c < 8; ++c) acc[r][c] += av[r] * wv[c];
    }
    if (tile < 7){ sstore(1 - buf); __syncthreads(); }
  }

  float asv[8], adv[8];
  #pragma unroll
  for (int c = 0; c < 8; ++c){ asv[c] = a_s[c0 + c]; adv[c] = a_d[c0 + c]; }

  #pragma unroll
  for (int r = 0; r < 4; ++r){
    int n = n0 + r0 + r;
    if (n >= N) continue;
    float4 o0 = make_float4(acc[r][0], acc[r][1], acc[r][2], acc[r][3]);
    float4 o1 = make_float4(acc[r][4], acc[r][5], acc[r][6], acc[r][7]);
    float4* hp = (float4*)&h[(size_t)n * 128 + c0];
    hp[0] = o0; hp[1] = o1;
    float ps = 0.f, pd = 0.f;
    #pragma unroll
    for (int c = 0; c < 8; ++c){ ps += acc[r][c] * asv[c]; pd += acc[r][c] * adv[c]; }
    ps += __shfl_xor(ps, 1); ps += __shfl_xor(ps, 2);
    pd += __shfl_xor(pd, 1); pd += __shfl_xor(pd, 2);
    if ((tx & 3) == 0){
      as_[n * 4 + (tx >> 2)] = ps;
      ad_[n * 4 + (tx >> 2)] = pd;
    }
  }
}

// ---------------- layer 3 ----------------
__global__ void __launch_bounds__(256) transform3_k(const float* __restrict__ A, const float* __restrict__ W3,
                                                    const float* __restrict__ a_s3, const float* __restrict__ a_d3,
                                                    float* __restrict__ h3, float* __restrict__ as_, float* __restrict__ ad_,
                                                    int N){
  int node = blockIdx.x * 8 + (threadIdx.x >> 5);
  if (node >= N) return;
  int j = threadIdx.x & 31;
  float4 a = ((const float4*)A)[(size_t)node * 32 + j];
  float4 w = ((const float4*)W3)[j];
  float acc = a.x * w.x + a.y * w.y + a.z * w.z + a.w * w.w;
  #pragma unroll
  for (int off = 16; off; off >>= 1) acc += __shfl_xor(acc, off, 32);
  if (j == 0){
    h3[node]  = acc;
    as_[node] = acc * a_s3[0];
    ad_[node] = acc * a_d3[0];
  }
}

// single pass, no max, 64 lanes per node
__global__ void __launch_bounds__(256) node_aggr3_k(const int* __restrict__ row, const int* __restrict__ csr_src,
                                                    const float* __restrict__ as_, const float* __restrict__ ad_,
                                                    const float* __restrict__ h3, const float* __restrict__ b3,
                                                    float* __restrict__ out, int N){
  int node = blockIdx.x * 4 + (threadIdx.x >> 6);
  if (node >= N) return;
  int j = threadIdx.x & 63;
  int start = row[node], end = row[node + 1];
  float adv = ad_[node];
  float s = 0.f, acc = 0.f;
  for (int i = start + j; i < end; i += 64){
    int src = csr_src[i];
    float p = __expf(leaky(as_[src] + adv));
    s += p; acc += h3[src] * p;
  }
  #pragma unroll
  for (int off = 32; off; off >>= 1){ s += __shfl_xor(s, off); acc += __shfl_xor(acc, off); }
  if (j == 0) out[node] = acc / s + b3[0];
}

// ---------------- launch ----------------
extern "C" void kernel_launch(void* const* d_in, const int* in_sizes, int n_in,
                              void* d_out, int out_size, void* d_ws, size_t ws_size,
                              hipStream_t stream){
  const float* x   = (const float*)d_in[0];
  const int*   ei  = (const int*)  d_in[1];
  const float* W1  = (const float*)d_in[2];
  const float* as1 = (const float*)d_in[3];
  const float* ad1 = (const float*)d_in[4];
  const float* b1  = (const float*)d_in[5];
  const float* W2  = (const float*)d_in[6];
  const float* as2 = (const float*)d_in[7];
  const float* ad2 = (const float*)d_in[8];
  const float* b2  = (const float*)d_in[9];
  const float* W3  = (const float*)d_in[10];
  const float* as3 = (const float*)d_in[11];
  const float* ad3 = (const float*)d_in[12];
  const float* b3  = (const float*)d_in[13];

  const int N    = in_sizes[0];       // IN_C = 1
  const int Eg   = in_sizes[1] / 2;
  const int Etot = Eg + N;
  const int* esrc = ei;
  const int* edst = ei + Eg;

  char* w = (char*)d_ws;
  auto carve = [&](size_t bytes)->char*{
    char* p = w; w += (bytes + 15) & ~size_t(15); return p;
  };
  float* hbuf   = (float*)carve((size_t)N * 128 * 4);
  float* actA   = (float*)carve((size_t)N * 128 * 4);
  float* asb    = (float*)carve((size_t)N * 4 * 4);
  float* adb    = (float*)carve((size_t)N * 4 * 4);
  float* h3b    = (float*)carve((size_t)N * 4);
  float* as3b   = (float*)carve((size_t)N * 4);
  float* ad3b   = (float*)carve((size_t)N * 4);
  int*   deg    = (int*)  carve((size_t)N * 4);
  int*   rowp   = (int*)  carve((size_t)(N + 1) * 4);
  int*   cursor = (int*)  carve((size_t)N * 4);
  int*   csr_src= (int*)  carve((size_t)Etot * 4);
  float* dAdD   = (float*)carve(8 * 4);
  int*   bsum   = (int*)  carve(64 * 4);
  int*   boff   = (int*)  carve(64 * 4);

  const int B = 256;
  auto cdiv = [](int a, int b){ return (a + b - 1) / b; };
  const int nb = cdiv(N, 2048);   // 25 for N=50000 (must be <= 64)

  // ---- CSR build (shared by all 3 layers) ----
  fill_i32_k<<<cdiv(N, B), B, 0, stream>>>(deg, 0, N);
  hist_k<<<cdiv(Etot, B), B, 0, stream>>>(edst, deg, Eg, Etot);
  scan_part_k<<<nb, B, 0, stream>>>(deg, bsum, N);
  scan_tops_k<<<1, 64, 0, stream>>>(bsum, boff, rowp, nb, N);
  scan_write_k<<<nb, B, 0, stream>>>(deg, boff, rowp, cursor, N);
  scatter_k<<<cdiv(Etot, B), B, 0, stream>>>(esrc, edst, cursor, csr_src, Eg, Etot);

  // ---- layer 1 (rank-1: no transform, scalar gather) ----
  dots1_k<<<1, 128, 0, stream>>>(W1, as1, ad1, dAdD);
  node_aggr1_k<<<cdiv(N, 8), B, 0, stream>>>(rowp, csr_src, x, dAdD,
                                             (const float4*)W1, (const float4*)b1,
                                             (float4*)actA, N);

  // ---- layer 2 ----
  gemm2_k<<<cdiv(N, 64), B, 0, stream>>>(actA, W2, as2, ad2, hbuf, asb, adb, N);
  node_aggr_k<true><<<cdiv(N, 8), B, 0, stream>>>(rowp, csr_src, asb, adb,
                                                  (const float4*)hbuf, (const float4*)b2,
                                                  (float4*)actA, N);

  // ---- layer 3 (H=1, C=1) ----
  transform3_k<<<cdiv(N, 8), B, 0, stream>>>(actA, W3, as3, ad3, h3b, as3b, ad3b, N);
  node_aggr3_k<<<cdiv(N, 4), B, 0, stream>>>(rowp, csr_src, as3b, ad3b, h3b, b3, (float*)d_out, N);
}